// Round 8
// baseline (542.837 us; speedup 1.0000x reference)
//
#include <hip/hip_runtime.h>
#include <hip/hip_bf16.h>

// EncoderCell, bf16-MFMA, round 8 (= round 7 + fixed-bound softmax).
//   attn_mfma: wave-independent flash attention; K/V/Q fragments direct
//              global->register; fixed softmax rebase (p = 2^(s*SCL+mask'-16),
//              mask' = mask*log2e-16 precomputed fp32) -> no online rescale,
//              AGPR accumulators untouched in loop; K-split x2, merge = add.
//   V-projection computed pre-transposed (C' = WvT . v^T).
// ws (MiB): [0,8) qb->vhT ; [8,16) kb->zb ; [16,24) vb->xb ; [24,32) WqkvdT ;
//   [32,40) W1T ; [40,48) W2T ; [48,64) qh|kh -> zd0/y0 ; [64,80) zd1/y1 ;
//   [80,96) x ; [96,112) mkl fp32 (dead at FF1) ; [96,128) h1. = 128 MiB.

#define SEQ 2048
#define DM  1024
#define LNEPS 1e-5f
#define SCL  0.1803368801f   // 0.125 * log2(e)
#define PW   5120            // per-wave LDS region, shorts (P 4608 + l 512)

typedef __attribute__((ext_vector_type(8))) short bf16x8;
typedef __attribute__((ext_vector_type(4))) float f32x4;

#define GAS __attribute__((address_space(1)))
#define LAS __attribute__((address_space(3)))

static __device__ __forceinline__ void gl_lds16(const unsigned short* g, unsigned short* l) {
    __builtin_amdgcn_global_load_lds((const GAS void*)g, (LAS void*)l, 16, 0, 0);
}

static __device__ __forceinline__ unsigned short f2bf(float f) {
    unsigned u = __builtin_bit_cast(unsigned, f);
    u += 0x7fffu + ((u >> 16) & 1u);   // RNE
    return (unsigned short)(u >> 16);
}

static __device__ __forceinline__ float bf2f(unsigned short s) {
    return __builtin_bit_cast(float, (unsigned)s << 16);
}

// pack two fp32 -> two bf16 (truncation) in one v_perm_b32
static __device__ __forceinline__ unsigned pack_bf16_trunc(float a, float b) {
    return __builtin_amdgcn_perm(__builtin_bit_cast(unsigned, b),
                                 __builtin_bit_cast(unsigned, a), 0x07060302u);
}

// ------------------------------------------------------------------
// C[M,N] (per-z slice) = A[M,Klen] @ Bt[N,Klen]^T. bias only on z==0.
// ------------------------------------------------------------------
__global__ __launch_bounds__(256) void gemm_bf16(
    const unsigned short* __restrict__ A, const unsigned short* __restrict__ Bt,
    float* __restrict__ Cf, unsigned short* __restrict__ Cb,
    int M, int N, int Klen, int lda, int ldb,
    size_t sA, size_t sB, size_t sC,
    const float* __restrict__ bias, int ep)
{
    __shared__ unsigned short As[128 * 32];
    __shared__ unsigned short Bs[128 * 32];

    const int t = threadIdx.x, lane = t & 63, w = t >> 6;
    const int wm = w >> 1, wn = w & 1;
    const int m0 = blockIdx.y * 128, n0 = blockIdx.x * 128;
    A  += (size_t)blockIdx.z * sA;
    Bt += (size_t)blockIdx.z * sB;
    const size_t cbase = (size_t)blockIdx.z * sC;
    const int l15 = lane & 15, l16 = lane >> 4;
    const int ar = lane >> 2, ac = (lane & 3) * 8;

    f32x4 acc[4][4];
    #pragma unroll
    for (int i = 0; i < 4; i++)
        #pragma unroll
        for (int j = 0; j < 4; j++)
            acc[i][j] = (f32x4){0.f, 0.f, 0.f, 0.f};

    for (int k0 = 0; k0 < Klen; k0 += 32) {
        __syncthreads();
        #pragma unroll
        for (int i = 0; i < 2; i++) {
            const int rg = w * 2 + i;
            gl_lds16(&A [(size_t)(m0 + rg * 16 + ar) * lda + k0 + ac], &As[rg * 512]);
            gl_lds16(&Bt[(size_t)(n0 + rg * 16 + ar) * ldb + k0 + ac], &Bs[rg * 512]);
        }
        __syncthreads();

        bf16x8 af[4], bfr[4];
        #pragma unroll
        for (int i = 0; i < 4; i++) {
            af[i]  = *(const bf16x8*)&As[(wm * 64 + i * 16 + l15) * 32 + l16 * 8];
            bfr[i] = *(const bf16x8*)&Bs[(wn * 64 + i * 16 + l15) * 32 + l16 * 8];
        }
        #pragma unroll
        for (int mi = 0; mi < 4; mi++)
            #pragma unroll
            for (int ni = 0; ni < 4; ni++)
                acc[mi][ni] = __builtin_amdgcn_mfma_f32_16x16x32_bf16(
                    af[mi], bfr[ni], acc[mi][ni], 0, 0, 0);
    }

    #pragma unroll
    for (int ni = 0; ni < 4; ni++) {
        const int col = n0 + wn * 64 + ni * 16 + l15;
        const float bv = (ep && blockIdx.z == 0) ? bias[col] : 0.f;
        #pragma unroll
        for (int mi = 0; mi < 4; mi++) {
            #pragma unroll
            for (int r = 0; r < 4; r++) {
                const int row = m0 + wm * 64 + mi * 16 + l16 * 4 + r;
                float vv = acc[mi][ni][r] + bv;
                if (ep == 2) vv = fmaxf(vv, 0.f);
                if (Cf) Cf[cbase + (size_t)row * N + col] = vv;
                else    Cb[cbase + (size_t)row * N + col] = f2bf(vv);
            }
        }
    }
}

// ------------------------------------------------------------------
// Flash attention, fixed softmax rebase. grid = 512 x 256 = 2048 waves.
// Wave W = bid*4+w: pair P = W>>1: qt=P&31, h=(P>>5)&15, b=P>>9 ; ks=W&1.
// Wave: 64 q-rows (q0=qt*64) x keys [ks*1024, ks*1024+1024).
// p = 2^(s*SCL + mkl), mkl = mask*log2e - 16 (fp32). No per-iter rescale.
// Partner waves merge (O,l) by ADDITION via LDS + one barrier.
// vhT is [1024][4096]: row = h*64+d, col = b*2048 + s.
// ------------------------------------------------------------------
__global__ __launch_bounds__(256, 2) void attn_mfma(
    const unsigned short* __restrict__ qh, const unsigned short* __restrict__ kh,
    const unsigned short* __restrict__ vhT, const float* __restrict__ mkl,
    unsigned short* __restrict__ z)
{
    __shared__ unsigned short Ps[4][PW];   // per-wave: P tile / merge scratch

    const int t = threadIdx.x, lane = t & 63, w = t >> 6;
    const int W = blockIdx.x * 4 + w;
    const int P = W >> 1, ks = W & 1;
    const int qt = P & 31, h = (P >> 5) & 15, b = P >> 9;
    const int q0 = qt * 64;
    const int l15 = lane & 15, l16 = lane >> 4;
    unsigned short* ps = &Ps[w][0];

    const size_t qrow = (size_t)(b * SEQ + q0);
    const size_t krow = (size_t)(b * SEQ);
    const size_t vrow = (size_t)(h * 64);        // + d ; col stride 4096
    const int    vcol = b * SEQ;

    // Q B-fragments, persistent: bQ[qi][half]
    bf16x8 bQ[4][2];
    #pragma unroll
    for (int qi = 0; qi < 4; qi++)
        #pragma unroll
        for (int hf = 0; hf < 2; hf++)
            bQ[qi][hf] = *(const bf16x8*)&qh[(qrow + qi * 16 + l15) * DM + h * 64 + hf * 32 + l16 * 8];

    float l_i[4] = {0.f, 0.f, 0.f, 0.f};
    f32x4 o4[4][4];                               // [mi(d)][qi] — AGPRs, untouched in loop
    #pragma unroll
    for (int mi = 0; mi < 4; mi++)
        #pragma unroll
        for (int qi = 0; qi < 4; qi++)
            o4[mi][qi] = (f32x4){0.f, 0.f, 0.f, 0.f};

    const float* mrow = mkl + (size_t)(q0 + l15) * SEQ;

    const int kt0 = ks * 16;
    for (int kt = kt0; kt < kt0 + 16; kt++) {
        const int k0 = kt * 64;

        // K A-fragments: aK[ki][half]
        bf16x8 aK[4][2];
        #pragma unroll
        for (int ki = 0; ki < 4; ki++)
            #pragma unroll
            for (int hf = 0; hf < 2; hf++)
                aK[ki][hf] = *(const bf16x8*)&kh[(krow + k0 + ki * 16 + l15) * DM + h * 64 + hf * 32 + l16 * 8];

        #pragma unroll
        for (int qi = 0; qi < 4; qi++) {
            // mask' fp32: keys ki*16 + l16*4 .. +3 for q-row qi*16+l15
            float4 mv[4];
            #pragma unroll
            for (int ki = 0; ki < 4; ki++)
                mv[ki] = *(const float4*)&mrow[(size_t)qi * 16 * SEQ + k0 + ki * 16 + l16 * 4];

            f32x4 s4[4];
            #pragma unroll
            for (int ki = 0; ki < 4; ki++) {
                f32x4 a0 = (f32x4){0.f, 0.f, 0.f, 0.f};
                a0 = __builtin_amdgcn_mfma_f32_16x16x32_bf16(aK[ki][0], bQ[qi][0], a0, 0, 0, 0);
                s4[ki] = __builtin_amdgcn_mfma_f32_16x16x32_bf16(aK[ki][1], bQ[qi][1], a0, 0, 0, 0);
            }

            // p = 2^(s*SCL + mask') ; accumulate l in-lane; pack P -> LDS
            #pragma unroll
            for (int ki = 0; ki < 4; ki++) {
                float p0 = exp2f(s4[ki][0] * SCL + mv[ki].x);
                float p1 = exp2f(s4[ki][1] * SCL + mv[ki].y);
                float p2 = exp2f(s4[ki][2] * SCL + mv[ki].z);
                float p3 = exp2f(s4[ki][3] * SCL + mv[ki].w);
                l_i[qi] += (p0 + p1) + (p2 + p3);
                uint2 pk;
                pk.x = pack_bf16_trunc(p0, p1);
                pk.y = pack_bf16_trunc(p2, p3);
                *(uint2*)&ps[(qi * 16 + l15) * 72 + ki * 16 + l16 * 4] = pk;
            }
        }

        // V A-fragments: aV[mi][half] (V^T [d][key])
        bf16x8 aV[4][2];
        #pragma unroll
        for (int mi = 0; mi < 4; mi++)
            #pragma unroll
            for (int hf = 0; hf < 2; hf++)
                aV[mi][hf] = *(const bf16x8*)&vhT[(vrow + mi * 16 + l15) * 4096 + vcol + k0 + hf * 32 + l16 * 8];

        // P B-fragments from wave-private LDS
        bf16x8 bP[4][2];
        #pragma unroll
        for (int qi = 0; qi < 4; qi++)
            #pragma unroll
            for (int hf = 0; hf < 2; hf++)
                bP[qi][hf] = *(const bf16x8*)&ps[(qi * 16 + l15) * 72 + hf * 32 + l16 * 8];

        #pragma unroll
        for (int mi = 0; mi < 4; mi++)
            #pragma unroll
            for (int qi = 0; qi < 4; qi++) {
                o4[mi][qi] = __builtin_amdgcn_mfma_f32_16x16x32_bf16(aV[mi][0], bP[qi][0], o4[mi][qi], 0, 0, 0);
                o4[mi][qi] = __builtin_amdgcn_mfma_f32_16x16x32_bf16(aV[mi][1], bP[qi][1], o4[mi][qi], 0, 0, 0);
            }
    }

    // finalize l: reduce across l16 groups (lane's l applies to q = qi*16+l15)
    #pragma unroll
    for (int qi = 0; qi < 4; qi++) {
        l_i[qi] += __shfl_xor(l_i[qi], 16);
        l_i[qi] += __shfl_xor(l_i[qi], 32);
    }

    // ---- merge partner halves (w, w^1): plain addition ----
    #pragma unroll
    for (int mi = 0; mi < 4; mi++)
        #pragma unroll
        for (int qi = 0; qi < 4; qi++) {
            uint2 pk;
            pk.x = pack_bf16_trunc(o4[mi][qi][0], o4[mi][qi][1]);
            pk.y = pack_bf16_trunc(o4[mi][qi][2], o4[mi][qi][3]);
            *(uint2*)&ps[(mi * 4 + qi) * 256 + lane * 4] = pk;
        }
    float* fml = (float*)&ps[4608];   // 256 floats = 512 shorts, ends at PW
    #pragma unroll
    for (int qi = 0; qi < 4; qi++) fml[lane * 4 + qi] = l_i[qi];
    __syncthreads();

    if (ks == 0) {
        const unsigned short* pp = &Ps[w ^ 1][0];
        const float* pml = (const float*)&pp[4608];
        float inv[4];
        #pragma unroll
        for (int qi = 0; qi < 4; qi++)
            inv[qi] = 1.f / (l_i[qi] + pml[lane * 4 + qi]);
        #pragma unroll
        for (int mi = 0; mi < 4; mi++)
            #pragma unroll
            for (int qi = 0; qi < 4; qi++) {
                const ushort4 ov = *(const ushort4*)&pp[(mi * 4 + qi) * 256 + lane * 4];
                ushort4 ok;
                ok.x = f2bf((o4[mi][qi][0] + bf2f(ov.x)) * inv[qi]);
                ok.y = f2bf((o4[mi][qi][1] + bf2f(ov.y)) * inv[qi]);
                ok.z = f2bf((o4[mi][qi][2] + bf2f(ov.z)) * inv[qi]);
                ok.w = f2bf((o4[mi][qi][3] + bf2f(ov.w)) * inv[qi]);
                *(ushort4*)&z[(qrow + qi * 16 + l15) * DM + h * 64 + mi * 16 + l16 * 4] = ok;
            }
    }
}

// ------------------------------------------------------------------
__global__ __launch_bounds__(256) void cast3_bf16(
    const float* __restrict__ a0, const float* __restrict__ a1, const float* __restrict__ a2,
    unsigned short* __restrict__ out)
{
    const float* src = blockIdx.z == 0 ? a0 : (blockIdx.z == 1 ? a1 : a2);
    const size_t i = ((size_t)blockIdx.x * 256 + threadIdx.x) * 4;
    const float4 v = *(const float4*)&src[i];
    ushort4 o; o.x = f2bf(v.x); o.y = f2bf(v.y); o.z = f2bf(v.z); o.w = f2bf(v.w);
    *(ushort4*)&out[(size_t)blockIdx.z * ((size_t)SEQ * 2 * DM) + i] = o;
}

// mkl = mask * log2(e) - 16  (fixed softmax rebase folded in)
__global__ __launch_bounds__(256) void scale_mask(
    const float* __restrict__ m, float* __restrict__ o)
{
    const size_t i = ((size_t)blockIdx.x * 256 + threadIdx.x) * 4;
    float4 v = *(const float4*)&m[i];
    v.x = v.x * 1.44269504f - 16.f; v.y = v.y * 1.44269504f - 16.f;
    v.z = v.z * 1.44269504f - 16.f; v.w = v.w * 1.44269504f - 16.f;
    *(float4*)&o[i] = v;
}

// 4x W[1024][1024] fp32 -> Wt[z][1024][1024] bf16 (transposed) ; grid (16,16,4)
__global__ __launch_bounds__(256) void transpose_cast4(
    const float* __restrict__ p0, const float* __restrict__ p1,
    const float* __restrict__ p2, const float* __restrict__ p3,
    unsigned short* __restrict__ Wt)
{
    const float* W = blockIdx.z == 0 ? p0 : (blockIdx.z == 1 ? p1 :
                     (blockIdx.z == 2 ? p2 : p3));
    unsigned short* dst = Wt + (size_t)blockIdx.z * 1024 * 1024;
    __shared__ float ts[64][65];
    const int n0 = blockIdx.x * 64, k0 = blockIdx.y * 64;
    const int t = threadIdx.x, r = t >> 4, c4 = (t & 15) * 4;
    #pragma unroll
    for (int i = 0; i < 4; i++) {
        const float4 v = *(const float4*)&W[(size_t)(k0 + r + i * 16) * 1024 + n0 + c4];
        ts[r + i * 16][c4 + 0] = v.x; ts[r + i * 16][c4 + 1] = v.y;
        ts[r + i * 16][c4 + 2] = v.z; ts[r + i * 16][c4 + 3] = v.w;
    }
    __syncthreads();
    #pragma unroll
    for (int i = 0; i < 4; i++) {
        const int n = r + i * 16;
        ushort4 o;
        o.x = f2bf(ts[c4 + 0][n]); o.y = f2bf(ts[c4 + 1][n]);
        o.z = f2bf(ts[c4 + 2][n]); o.w = f2bf(ts[c4 + 3][n]);
        *(ushort4*)&dst[(size_t)(n0 + n) * 1024 + k0 + c4] = o;
    }
}

// W[K][N] fp32 -> Wt[N][K] bf16 ; grid (N/64, K/64)
__global__ __launch_bounds__(256) void transpose_cast(
    const float* __restrict__ W, unsigned short* __restrict__ Wt, int K, int N)
{
    __shared__ float ts[64][65];
    const int n0 = blockIdx.x * 64, k0 = blockIdx.y * 64;
    const int t = threadIdx.x, r = t >> 4, c4 = (t & 15) * 4;
    #pragma unroll
    for (int i = 0; i < 4; i++) {
        const float4 v = *(const float4*)&W[(size_t)(k0 + r + i * 16) * N + n0 + c4];
        ts[r + i * 16][c4 + 0] = v.x; ts[r + i * 16][c4 + 1] = v.y;
        ts[r + i * 16][c4 + 2] = v.z; ts[r + i * 16][c4 + 3] = v.w;
    }
    __syncthreads();
    #pragma unroll
    for (int i = 0; i < 4; i++) {
        const int n = r + i * 16;
        ushort4 o;
        o.x = f2bf(ts[c4 + 0][n]); o.y = f2bf(ts[c4 + 1][n]);
        o.z = f2bf(ts[c4 + 2][n]); o.w = f2bf(ts[c4 + 3][n]);
        *(ushort4*)&Wt[(size_t)(n0 + n) * K + k0 + c4] = o;
    }
}

// ------------------------------------------------------------------
// LN + residual with optional second partial input (split-K sum).
// mode 0: out = LN(a+a2)*g+be + r (+bf16 copy) ; mode 1: out = LN(a+a2+r)*g+be
// ------------------------------------------------------------------
__global__ __launch_bounds__(256) void ln_res(
    const float* __restrict__ a, const float* __restrict__ a2,
    const float* __restrict__ r,
    const float* __restrict__ g, const float* __restrict__ be,
    float* __restrict__ out, unsigned short* __restrict__ outb, int mode)
{
    __shared__ float redls[8];
    const int row = blockIdx.x, t = threadIdx.x;
    const size_t base = (size_t)row * DM;

    float vals[4], s = 0.f, sq = 0.f;
    #pragma unroll
    for (int i = 0; i < 4; i++) {
        const int c = t + 256 * i;
        float x = a[base + c];
        if (a2) x += a2[base + c];
        if (mode == 1) x += r[base + c];
        vals[i] = x; s += x; sq += x * x;
    }
    #pragma unroll
    for (int off = 32; off > 0; off >>= 1) { s += __shfl_down(s, off); sq += __shfl_down(sq, off); }
    if ((t & 63) == 0) { redls[t >> 6] = s; redls[4 + (t >> 6)] = sq; }
    __syncthreads();
    s  = redls[0] + redls[1] + redls[2] + redls[3];
    sq = redls[4] + redls[5] + redls[6] + redls[7];

    const float mu  = s * (1.f / 1024.f);
    const float var = sq * (1.f / 1024.f) - mu * mu;
    const float rs  = rsqrtf(var + LNEPS);
    #pragma unroll
    for (int i = 0; i < 4; i++) {
        const int c = t + 256 * i;
        float y = (vals[i] - mu) * rs * g[c] + be[c];
        if (mode == 0) y += r[base + c];
        out[base + c] = y;
        if (outb) outb[base + c] = f2bf(y);
    }
}

// ------------------------------------------------------------------
extern "C" void kernel_launch(void* const* d_in, const int* in_sizes, int n_in,
                              void* d_out, int out_size, void* d_ws, size_t ws_size,
                              hipStream_t stream)
{
    const float* q    = (const float*)d_in[0];
    const float* k    = (const float*)d_in[1];
    const float* v    = (const float*)d_in[2];
    const float* mask = (const float*)d_in[4];
    const float* Wq   = (const float*)d_in[5];
    const float* Wk   = (const float*)d_in[6];
    const float* Wv   = (const float*)d_in[7];
    const float* Wd   = (const float*)d_in[8];
    const float* W1   = (const float*)d_in[9];
    const float* b1   = (const float*)d_in[10];
    const float* W2   = (const float*)d_in[11];
    const float* b2   = (const float*)d_in[12];
    const float* g1   = (const float*)d_in[13];
    const float* be1  = (const float*)d_in[14];
    const float* g2   = (const float*)d_in[15];
    const float* be2  = (const float*)d_in[16];
    float* out = (float*)d_out;

    char* WS = (char*)d_ws;
    const size_t MiB = 1u << 20;
    const size_t ND  = (size_t)4096 * 1024;

    unsigned short* qb  = (unsigned short*)(WS + 0);          //  8 MiB
    unsigned short* vhT = (unsigned short*)(WS + 0);          //  8 MiB (reuse qb)
    unsigned short* zb  = (unsigned short*)(WS + 8 * MiB);    //  8 MiB (reuse kb)
    unsigned short* xb  = (unsigned short*)(WS + 16 * MiB);   //  8 MiB (reuse vb)
    unsigned short* Wqt = (unsigned short*)(WS + 24 * MiB);   //  8 MiB WqT|WkT|WvT|WdT
    unsigned short* W1t = (unsigned short*)(WS + 32 * MiB);   //  8 MiB
    unsigned short* W2t = (unsigned short*)(WS + 40 * MiB);   //  8 MiB
    unsigned short* qh  = (unsigned short*)(WS + 48 * MiB);   // 16 MiB qh|kh
    float*          zd0 = (float*)(WS + 48 * MiB);            // 16 MiB (reuse qh|kh)
    float*          zd1 = (float*)(WS + 64 * MiB);            // 16 MiB
    float*          x   = (float*)(WS + 80 * MiB);            // 16 MiB
    float*          mkl = (float*)(WS + 96 * MiB);            // 16 MiB (dead at FF1)
    unsigned short* h1  = (unsigned short*)(WS + 96 * MiB);   // 32 MiB
    float*          y0  = (float*)(WS + 48 * MiB);
    float*          y1  = (float*)(WS + 64 * MiB);

    unsigned short* kb  = qb + ND;      // [8,16)
    unsigned short* vb  = qb + 2 * ND;  // [16,24)
    unsigned short* kh  = qh + ND;
    unsigned short* WvT = Wqt + 2 * 1024 * 1024;
    unsigned short* Wdt = Wqt + 3 * 1024 * 1024;

    const dim3 blk(256);

    cast3_bf16<<<dim3(4096, 1, 3), blk, 0, stream>>>(q, k, v, qb);
    scale_mask<<<dim3(4096), blk, 0, stream>>>(mask, mkl);
    transpose_cast4<<<dim3(16, 16, 4), blk, 0, stream>>>(Wq, Wk, Wv, Wd, Wqt);
    transpose_cast<<<dim3(64, 16), blk, 0, stream>>>(W1, W1t, 1024, 4096);
    transpose_cast<<<dim3(16, 64), blk, 0, stream>>>(W2, W2t, 4096, 1024);

    // Q,K projections (z = batch of 2) -> qh, kh
    gemm_bf16<<<dim3(8, 32, 2), blk, 0, stream>>>(qb, Wqt, nullptr, qh,
        4096, 1024, 1024, 1024, 1024, ND, (size_t)1024 * 1024, ND, nullptr, 0);

    // V projection, pre-transposed: vhT[1024][4096] = WvT . vb^T (overwrites qb)
    gemm_bf16<<<dim3(32, 8, 1), blk, 0, stream>>>(WvT, vb, nullptr, vhT,
        1024, 4096, 1024, 1024, 1024, 0, 0, 0, nullptr, 0);

    attn_mfma<<<dim3(512), blk, 0, stream>>>(qh, kh, vhT, mkl, zb);

    // out-proj, split-K x2 -> zd0/zd1
    gemm_bf16<<<dim3(8, 32, 2), blk, 0, stream>>>(zb, Wdt, zd0, nullptr,
        4096, 1024, 512, 1024, 1024, 512, 512, ND, nullptr, 0);

    // LN1: x = LN(zd0+zd1) + q
    ln_res<<<dim3(4096), blk, 0, stream>>>(zd0, zd1, q, g1, be1, x, xb, 0);

    // FFN
    gemm_bf16<<<dim3(32, 32, 1), blk, 0, stream>>>(xb, W1t, nullptr, h1,
        4096, 4096, 1024, 1024, 1024, 0, 0, 0, b1, 2);
    gemm_bf16<<<dim3(8, 32, 2), blk, 0, stream>>>(h1, W2t, y0, nullptr,
        4096, 1024, 2048, 4096, 4096, 2048, 2048, ND, b2, 1);

    // LN2: out = LN(y0+y1+x)
    ln_res<<<dim3(4096), blk, 0, stream>>>(y0, y1, x, g2, be2, out, nullptr, 1);
}